// Round 1
// baseline (107.078 us; speedup 1.0000x reference)
//
#include <hip/hip_runtime.h>

// sample_pdf (NeRF, det=True): N_RAYS x {bins[127], weights[126]} -> samples[128]
// One wave (64 lanes) per ray; 4 rays per 256-thread block.

#define NBINS 127   // bins per ray == cdf length
#define M     126   // weights per ray
#define NS    128   // samples per ray

__global__ __launch_bounds__(256) void sample_pdf_kernel(
    const float* __restrict__ bins,
    const float* __restrict__ weights,
    float* __restrict__ out,
    int n_rays)
{
    __shared__ float s_cdf[4][128];
    __shared__ float s_bins[4][128];

    const int wave = threadIdx.x >> 6;
    const int lane = threadIdx.x & 63;
    const int ray  = blockIdx.x * 4 + wave;
    if (ray >= n_rays) return;

    const float* wrow = weights + (size_t)ray * M;
    const float* brow = bins    + (size_t)ray * NBINS;

    // ---- stage bins into LDS (127 floats) ----
    s_bins[wave][lane] = brow[lane];
    if (lane < 63) s_bins[wave][lane + 64] = brow[lane + 64];

    // ---- load 2 weights/lane (lanes 0..62 cover 126), +1e-5 ----
    float w0 = 0.0f, w1 = 0.0f;
    if (lane < 63) {
        float2 ww = *reinterpret_cast<const float2*>(wrow + 2 * lane);
        w0 = ww.x + 1e-5f;
        w1 = ww.y + 1e-5f;
    }
    const float pair = w0 + w1;

    // ---- wave-wide inclusive scan of pair sums ----
    float ps = pair;
    #pragma unroll
    for (int off = 1; off < 64; off <<= 1) {
        float o = __shfl_up(ps, off, 64);
        if (lane >= off) ps += o;
    }
    const float total = __shfl(ps, 62, 64);   // sum of all 126 weights
    const float inv   = 1.0f / total;
    const float excl  = ps - pair;            // sum w[0..2*lane-1]

    // cdf[0]=0; lane i<63 produces cdf[2i+1], cdf[2i+2]
    if (lane == 0) {
        s_cdf[wave][0]   = 0.0f;
        s_cdf[wave][127] = 2.0f;              // sentinel (never <= u)
    }
    if (lane < 63) {
        s_cdf[wave][2 * lane + 1] = (excl + w0) * inv;
        s_cdf[wave][2 * lane + 2] = ps * inv;
    }
    __syncthreads();

    const float* cdf = s_cdf[wave];
    const float* bn  = s_bins[wave];

    // ---- each lane: samples j = 2*lane, 2*lane+1 ----
    float2 res;
    #pragma unroll
    for (int s = 0; s < 2; ++s) {
        const int   j = 2 * lane + s;
        const float u = (float)(2 * j + 1) * (1.0f / 256.0f);  // exact, == linspace

        // branchless upper-bound count: pos = #{cdf[k] <= u}, k in [0,127)
        // steps sum to 127 so cand<=127 always; read index cand-1 <= 126.
        int pos = 0;
        #pragma unroll
        for (int step = 64; step > 0; step >>= 1) {
            const int cand = pos + step;
            pos = (cdf[cand - 1] <= u) ? cand : pos;
        }
        int below = pos - 1;            // pos >= 1 since cdf[0]=0 <= u
        if (below < 0) below = 0;
        int above = pos;
        if (above > NBINS - 1) above = NBINS - 1;

        const float cb = cdf[below];
        const float ca = cdf[above];
        const float bb = bn[below];
        const float ba = bn[above];

        float denom = ca - cb;
        denom = (denom < 1e-5f) ? 1.0f : denom;
        const float t = (u - cb) / denom;
        ((float*)&res)[s] = bb + t * (ba - bb);
    }

    // coalesced float2 store: out[ray*128 + 2*lane .. +1]
    *reinterpret_cast<float2*>(out + (size_t)ray * NS + 2 * lane) = res;
}

extern "C" void kernel_launch(void* const* d_in, const int* in_sizes, int n_in,
                              void* d_out, int out_size, void* d_ws, size_t ws_size,
                              hipStream_t stream) {
    const float* bins    = (const float*)d_in[0];
    const float* weights = (const float*)d_in[1];
    float* out = (float*)d_out;

    const int n_rays = in_sizes[0] / NBINS;
    const int blocks = (n_rays + 3) / 4;
    sample_pdf_kernel<<<blocks, 256, 0, stream>>>(bins, weights, out, n_rays);
}

// Round 3
// 99.003 us; speedup vs baseline: 1.0816x; 1.0816x over previous
//
#include <hip/hip_runtime.h>

// sample_pdf (NeRF, det=True), scatter formulation, boundary-consistent.
// u_j = (2j+1)/256 is a fixed grid, so interval k = [cdf[k], cdf[k+1])
// receives exactly the contiguous range [g(cdf[k]), g(cdf[k+1])),
// g(c) = ceil((256c - 1)/2) = #{j : u_j < c}.
// CRITICAL: adjacent lanes must evaluate g() on BITWISE-IDENTICAL boundary
// values, else an LDS slot can be skipped (stale garbage). Each lane computes
// only its own right edge c2 = ps*inv; left edge c0 arrives via shfl_up.

#define M     126   // weights per ray
#define NBINS 127   // bins per ray
#define NS    128   // samples per ray

__global__ __launch_bounds__(256) void sample_pdf_scatter(
    const float* __restrict__ bins,
    const float* __restrict__ weights,
    float* __restrict__ out,
    int n_rays)
{
    __shared__ float s_out[4][NS];

    const int wave = threadIdx.x >> 6;
    const int lane = threadIdx.x & 63;
    const int ray  = blockIdx.x * 4 + wave;
    if (ray >= n_rays) return;

    const float* wrow = weights + (size_t)ray * M;
    const float* brow = bins    + (size_t)ray * NBINS;

    // ---- bins endpoints for this lane's two intervals (2i and 2i+1) ----
    const int ia = 2 * lane;                                    // <= 126
    const int ib = (ia + 1 <= NBINS - 1) ? ia + 1 : NBINS - 1;  // clamp lane 63
    const float b_a = brow[ia];                    // bins[2i]
    const float b_b = brow[ib];                    // bins[2i+1]
    const float b_c = __shfl_down(b_a, 1, 64);     // bins[2i+2]

    // ---- weights (lanes 0..62 cover all 126), +1e-5 ----
    float w0 = 0.0f, w1 = 0.0f;
    if (lane < 63) {
        float2 ww = *reinterpret_cast<const float2*>(wrow + ia);
        w0 = ww.x + 1e-5f;
        w1 = ww.y + 1e-5f;
    }
    const float pair = w0 + w1;

    // ---- wave inclusive scan of pair sums ----
    float ps = pair;
    #pragma unroll
    for (int off = 1; off < 64; off <<= 1) {
        float o = __shfl_up(ps, off, 64);
        if (lane >= off) ps += o;
    }
    const float total = __shfl(ps, 62, 64);
    const float inv   = 1.0f / total;

    // ---- boundary cdf values; shared edges are bitwise-shared via shfl ----
    const float c2 = ps * inv;                     // cdf[2i+2] (own right edge)
    float c0 = __shfl_up(c2, 1, 64);               // cdf[2i]   (prev lane's c2)
    if (lane == 0) c0 = 0.0f;
    const float excl = ps - pair;
    const float c1   = (excl + w0) * inv;          // cdf[2i+1] (interior, owned)

    // ---- g(c) = ceil((256c - 1) * 0.5) ----
    int g0 = (int)ceilf(fmaf(c0, 256.0f, -1.0f) * 0.5f);
    int g1 = (int)ceilf(fmaf(c1, 256.0f, -1.0f) * 0.5f);
    int g2 = (int)ceilf(fmaf(c2, 256.0f, -1.0f) * 0.5f);
    if (lane == 62) g2 = NS;                       // cover the top end
    if (lane == 63) { g0 = 0; g1 = 0; g2 = 0; }    // lane 63 owns nothing
    // monotone clamp: can only create overlaps (harmless), never gaps
    g0 = max(0, min(g0, NS));
    g1 = max(g0, min(g1, NS));
    g2 = max(g1, min(g2, NS));

    // ---- per-interval slope = (b_r - b_l)/denom, denom<1e-5 -> 1 ----
    float dA = c1 - c0; dA = (dA < 1e-5f) ? 1.0f : dA;
    float dB = c2 - c1; dB = (dB < 1e-5f) ? 1.0f : dB;
    const float slA = (b_b - b_a) * __builtin_amdgcn_rcpf(dA);
    const float slB = (b_c - b_b) * __builtin_amdgcn_rcpf(dB);

    // ---- emit: j in [g0,g1) -> interval A, [g1,g2) -> interval B ----
    float* so = s_out[wave];
    for (int j = g0; j < g2; ++j) {
        const bool  inA = j < g1;
        const float cl  = inA ? c0  : c1;
        const float bl  = inA ? b_a : b_b;
        const float sl  = inA ? slA : slB;
        const float u   = fmaf((float)j, 0.0078125f, 0.00390625f); // (2j+1)/256
        so[j] = fmaf(u - cl, sl, bl);
    }

    // within-wave LDS is in-order; fence compiler scheduling only
    __builtin_amdgcn_wave_barrier();

    // ---- coalesced flush ----
    const float2 r = *reinterpret_cast<const float2*>(&so[2 * lane]);
    *reinterpret_cast<float2*>(out + (size_t)ray * NS + 2 * lane) = r;
}

extern "C" void kernel_launch(void* const* d_in, const int* in_sizes, int n_in,
                              void* d_out, int out_size, void* d_ws, size_t ws_size,
                              hipStream_t stream) {
    const float* bins    = (const float*)d_in[0];
    const float* weights = (const float*)d_in[1];
    float* out = (float*)d_out;

    const int n_rays = in_sizes[0] / NBINS;
    const int blocks = (n_rays + 3) / 4;
    sample_pdf_scatter<<<blocks, 256, 0, stream>>>(bins, weights, out, n_rays);
}